// Round 1
// baseline (358.665 us; speedup 1.0000x reference)
//
#include <hip/hip_runtime.h>

#define H 1024
#define QD 16
#define BATCH 4
#define SEQ 2048
#define MROWS 8192  // BATCH*SEQ

typedef __bf16 bf16x8 __attribute__((ext_vector_type(8)));
typedef __bf16 bf16x4 __attribute__((ext_vector_type(4)));
typedef float f32x4 __attribute__((ext_vector_type(4)));

__device__ __forceinline__ void async_g2l_16(const void* g, void* l) {
  __builtin_amdgcn_global_load_lds(
      (const __attribute__((address_space(1))) unsigned int*)g,
      (__attribute__((address_space(3))) unsigned int*)l, 16, 0, 0);
}

// ---------------- fp32 -> bf16 convert (x) ----------------
__global__ __launch_bounds__(256) void cvt_f32_bf16(const float* __restrict__ src,
                                                    __bf16* __restrict__ dst, int n) {
  int i = (blockIdx.x * 256 + threadIdx.x) * 4;
  if (i < n) {
    float4 f = *(const float4*)(src + i);
    bf16x4 o;
    o[0] = (__bf16)f.x; o[1] = (__bf16)f.y; o[2] = (__bf16)f.z; o[3] = (__bf16)f.w;
    *(bf16x4*)(dst + i) = o;
  }
}

// ---------------- fp32 [R][C] -> bf16 transposed [C][R] ----------------
__global__ __launch_bounds__(256) void transpose_cvt_f32_bf16(
    const float* __restrict__ src, __bf16* __restrict__ dst, int R, int C) {
  __shared__ float t[32][33];
  const int rb = blockIdx.y * 32, cb = blockIdx.x * 32;
  const int c = threadIdx.x & 31;
  const int r0 = threadIdx.x >> 5;
#pragma unroll
  for (int rr = r0; rr < 32; rr += 8)
    t[rr][c] = src[(long)(rb + rr) * C + cb + c];
  __syncthreads();
#pragma unroll
  for (int rr = r0; rr < 32; rr += 8)
    dst[(long)(cb + rr) * R + rb + c] = (__bf16)t[c][rr];
}

// ---------------- bf16 [R][C] -> bf16 transposed [C][R], batched ----------------
__global__ __launch_bounds__(256) void transpose_bf16_batched(
    const __bf16* __restrict__ src, __bf16* __restrict__ dst, int R, int C,
    long sS, long sD) {
  __shared__ __bf16 t[32][33];
  const __bf16* s = src + (long)blockIdx.z * sS;
  __bf16* d = dst + (long)blockIdx.z * sD;
  const int rb = blockIdx.y * 32, cb = blockIdx.x * 32;
  const int c = threadIdx.x & 31;
  const int r0 = threadIdx.x >> 5;
#pragma unroll
  for (int rr = r0; rr < 32; rr += 8)
    t[rr][c] = s[(long)(rb + rr) * C + cb + c];
  __syncthreads();
#pragma unroll
  for (int rr = r0; rr < 32; rr += 8)
    d[(long)(cb + rr) * R + rb + c] = t[c][rr];
}

// ---------------- Cqk[k][j] = (Wq|Wk) row k dot We col j, fp32 ----------------
__global__ __launch_bounds__(256) void k2_cqk(const float* __restrict__ Wq,
                                              const float* __restrict__ Wk,
                                              const float* __restrict__ We,
                                              float* __restrict__ Cqk) {
  const int gw = blockIdx.x * 4 + (threadIdx.x >> 6);  // 0..2047
  const int lane = threadIdx.x & 63;
  const int mat = gw & 1, k = gw >> 1;
  const float* Wrow = (mat ? Wk : Wq) + (long)k * H;
  const int col = lane & 15, q4 = lane >> 4;
  float acc = 0.f;
  for (int n0 = 0; n0 < 256; ++n0) {
    int n = q4 * 256 + n0;
    acc += Wrow[n] * We[n * QD + col];
  }
  acc += __shfl_xor(acc, 16);
  acc += __shfl_xor(acc, 32);
  if (lane < 16) Cqk[k * 32 + mat * 16 + col] = acc;
}

// ---------------- dvec[j] = (bq|bk)@We + be ----------------
__global__ void k2b_dvec(const float* __restrict__ bq, const float* __restrict__ bk,
                         const float* __restrict__ We, const float* __restrict__ be,
                         float* __restrict__ dvec) {
  int j = threadIdx.x;
  if (j < 32) {
    int mat = j >> 4, col = j & 15;
    const float* b = mat ? bk : bq;
    float acc = be[col];
    for (int n = 0; n < H; ++n) acc += b[n] * We[n * QD + col];
    dvec[j] = acc;
  }
}

// ---------------- embed: z = x@Cqk + dvec, normalize -> qq, kk (fp32) ----------------
__global__ __launch_bounds__(256) void k3_embed(const float* __restrict__ x,
                                                const float* __restrict__ Cqk,
                                                const float* __restrict__ dvec,
                                                float* __restrict__ qq,
                                                float* __restrict__ kk) {
  const int row = blockIdx.x * 4 + (threadIdx.x >> 6);
  const int lane = threadIdx.x & 63;
  const int col = lane & 31, half = lane >> 5;
  const float* xr = x + (long)row * H + half * 512;
  const float* Cp = Cqk + (long)(half * 512) * 32 + col;
  float a0 = 0.f, a1 = 0.f, a2 = 0.f, a3 = 0.f;
  for (int k = 0; k < 512; k += 4) {
    a0 += xr[k + 0] * Cp[(k + 0) * 32];
    a1 += xr[k + 1] * Cp[(k + 1) * 32];
    a2 += xr[k + 2] * Cp[(k + 2) * 32];
    a3 += xr[k + 3] * Cp[(k + 3) * 32];
  }
  float z = (a0 + a1) + (a2 + a3);
  z += __shfl_xor(z, 32);
  z += dvec[col];
  float s = z * z;
  s += __shfl_xor(s, 1);
  s += __shfl_xor(s, 2);
  s += __shfl_xor(s, 4);
  s += __shfl_xor(s, 8);
  float val = z * rsqrtf(s + 1e-8f);
  if (lane < 16) qq[(long)row * QD + col] = val;
  else if (lane < 32) kk[(long)row * QD + (col - 16)] = val;
}

// ---------------- P = exp((qq.kk)^2) bf16, rowsum fp32 ----------------
__global__ __launch_bounds__(256) void k4_weights(const float* __restrict__ qq,
                                                  const float* __restrict__ kk,
                                                  __bf16* __restrict__ P,
                                                  float* __restrict__ rowsum) {
  const int b = blockIdx.y;
  const int qbase = blockIdx.x * 16;
  const int tid = threadIdx.x;
  __shared__ float qs[16][16];
  __shared__ float rsh[16];
  qs[tid >> 4][tid & 15] =
      qq[((long)b * SEQ + qbase + (tid >> 4)) * QD + (tid & 15)];
  if (tid < 16) rsh[tid] = 0.f;
  __syncthreads();
  float sums[16];
#pragma unroll
  for (int q = 0; q < 16; ++q) sums[q] = 0.f;
  const float* kkb = kk + (long)b * SEQ * QD;
  __bf16* Pb = P + ((long)b * SEQ + qbase) * SEQ;
  for (int kc = 0; kc < 8; ++kc) {
    const int k = kc * 256 + tid;
    const float4* kp = (const float4*)(kkb + (long)k * QD);
    float4 k0 = kp[0], k1 = kp[1], k2 = kp[2], k3 = kp[3];
    float kr[16] = {k0.x, k0.y, k0.z, k0.w, k1.x, k1.y, k1.z, k1.w,
                    k2.x, k2.y, k2.z, k2.w, k3.x, k3.y, k3.z, k3.w};
#pragma unroll
    for (int q = 0; q < 16; ++q) {
      float d = 0.f;
#pragma unroll
      for (int j = 0; j < 16; ++j) d += qs[q][j] * kr[j];
      float wgt = __expf(d * d);
      sums[q] += wgt;
      Pb[(long)q * SEQ + k] = (__bf16)wgt;
    }
  }
#pragma unroll
  for (int q = 0; q < 16; ++q) {
    float vs = sums[q];
    vs += __shfl_xor(vs, 1);
    vs += __shfl_xor(vs, 2);
    vs += __shfl_xor(vs, 4);
    vs += __shfl_xor(vs, 8);
    vs += __shfl_xor(vs, 16);
    vs += __shfl_xor(vs, 32);
    if ((tid & 63) == 0) atomicAdd(&rsh[q], vs);
  }
  __syncthreads();
  if (tid < 16) rowsum[(long)b * SEQ + qbase + tid] = rsh[tid];
}

// ---------------- m97-style GEMM: C = A[MxK] @ Bt[NxK]^T (+bias)(*1/rowsum) ----------------
template <int OUTF32, int HASBIAS, int HASSCALE>
__global__ __launch_bounds__(256) void gemm_bt(
    const __bf16* __restrict__ A, const __bf16* __restrict__ Bt,
    void* __restrict__ Cout, const float* __restrict__ bias,
    const float* __restrict__ rowscale, int M, int N, int K,
    long sA, long sB, long sC, long sS) {
  __shared__ __bf16 Alds[128 * 64];
  __shared__ __bf16 Blds[128 * 64];
  const int tid = threadIdx.x;
  const int lane = tid & 63;
  const int w = tid >> 6;
  const int wm = w >> 1, wn = w & 1;
  const int bz = blockIdx.z;
  const long rowBase = (long)blockIdx.y * 128;
  const long colBase = (long)blockIdx.x * 128;
  const __bf16* Ab = A + (long)bz * sA;
  const __bf16* Bb = Bt + (long)bz * sB;

  const int srow = lane >> 3;
  const int skk = (lane & 7) * 8;

  const __bf16* ag[4];
  const __bf16* bg[4];
  __bf16* as_[4];
  __bf16* bs_[4];
#pragma unroll
  for (int j = 0; j < 4; ++j) {
    int r = j * 32 + w * 8;
    ag[j] = Ab + (rowBase + r + srow) * (long)K + skk;
    bg[j] = Bb + (colBase + r + srow) * (long)K + skk;
    as_[j] = &Alds[r * 64];
    bs_[j] = &Blds[r * 64];
  }

  f32x4 acc[4][4];
#pragma unroll
  for (int i = 0; i < 4; ++i)
#pragma unroll
    for (int j = 0; j < 4; ++j) {
      acc[i][j][0] = 0.f; acc[i][j][1] = 0.f; acc[i][j][2] = 0.f; acc[i][j][3] = 0.f;
    }

  const int afrag0 = (wm * 64 + (lane & 15)) * 64 + ((lane >> 4) * 8);
  const int bfrag0 = (wn * 64 + (lane & 15)) * 64 + ((lane >> 4) * 8);

  for (int k0 = 0; k0 < K; k0 += 64) {
#pragma unroll
    for (int j = 0; j < 4; ++j) {
      async_g2l_16(ag[j], as_[j]);
      async_g2l_16(bg[j], bs_[j]);
      ag[j] += 64;
      bg[j] += 64;
    }
    __syncthreads();
#pragma unroll
    for (int s = 0; s < 2; ++s) {
      bf16x8 af[4], bfv[4];
#pragma unroll
      for (int i = 0; i < 4; ++i) {
        af[i] = *(const bf16x8*)&Alds[afrag0 + i * 16 * 64 + s * 32];
        bfv[i] = *(const bf16x8*)&Blds[bfrag0 + i * 16 * 64 + s * 32];
      }
#pragma unroll
      for (int i = 0; i < 4; ++i)
#pragma unroll
        for (int j = 0; j < 4; ++j)
          acc[i][j] =
              __builtin_amdgcn_mfma_f32_16x16x32_bf16(af[i], bfv[j], acc[i][j], 0, 0, 0);
    }
    __syncthreads();
  }

  const float* rs = HASSCALE ? (rowscale + (long)bz * sS) : (const float*)nullptr;
  const long crow0 = rowBase + wm * 64 + ((lane >> 4) * 4);
  const long ccol0 = colBase + wn * 64 + (lane & 15);
#pragma unroll
  for (int i = 0; i < 4; ++i) {
#pragma unroll
    for (int j = 0; j < 4; ++j) {
      long col = ccol0 + j * 16;
      float bb = HASBIAS ? bias[col] : 0.f;
#pragma unroll
      for (int r = 0; r < 4; ++r) {
        long row = crow0 + i * 16 + r;
        float val = acc[i][j][r] + bb;
        if (HASSCALE) val *= 1.0f / rs[row];
        if (OUTF32)
          ((float*)Cout)[(long)bz * sC + row * N + col] = val;
        else
          ((__bf16*)Cout)[(long)bz * sC + row * N + col] = (__bf16)val;
      }
    }
  }
}

extern "C" void kernel_launch(void* const* d_in, const int* in_sizes, int n_in,
                              void* d_out, int out_size, void* d_ws, size_t ws_size,
                              hipStream_t stream) {
  const float* x = (const float*)d_in[0];
  const float* Wq = (const float*)d_in[1];
  const float* bq = (const float*)d_in[2];
  const float* Wk = (const float*)d_in[3];
  const float* bk = (const float*)d_in[4];
  const float* Wv = (const float*)d_in[5];
  const float* bv = (const float*)d_in[6];
  const float* We = (const float*)d_in[7];
  const float* be = (const float*)d_in[8];
  const float* Wo = (const float*)d_in[9];
  const float* bo = (const float*)d_in[10];
  float* out = (float*)d_out;

  char* ws = (char*)d_ws;
  size_t o = 0;
  auto alloc = [&](size_t n) {
    size_t r = o;
    o += (n + 255) & ~(size_t)255;
    return r;
  };
  __bf16* xbf = (__bf16*)(ws + alloc((size_t)MROWS * H * 2));
  __bf16* v = (__bf16*)(ws + alloc((size_t)MROWS * H * 2));
  __bf16* P = (__bf16*)(ws + alloc((size_t)BATCH * SEQ * SEQ * 2));
  __bf16* attn = (__bf16*)(ws + alloc((size_t)MROWS * H * 2));
  __bf16* Wvt = (__bf16*)(ws + alloc((size_t)H * H * 2));
  __bf16* Wot = (__bf16*)(ws + alloc((size_t)H * H * 2));
  float* Cqk = (float*)(ws + alloc((size_t)H * 32 * 4));
  float* dvec = (float*)(ws + alloc(32 * 4));
  float* qq = (float*)(ws + alloc((size_t)MROWS * QD * 4));
  float* kk = (float*)(ws + alloc((size_t)MROWS * QD * 4));
  float* rowsum = (float*)(ws + alloc((size_t)MROWS * 4));
  __bf16* v_t = xbf;  // alias: xbf dead after Kv GEMM (sequential stream ordering)
  if (ws_size < o) return;

  // 1) x -> bf16
  cvt_f32_bf16<<<MROWS * H / 1024, 256, 0, stream>>>(x, xbf, MROWS * H);
  // 2) Wv^T, Wo^T as bf16
  transpose_cvt_f32_bf16<<<dim3(32, 32), 256, 0, stream>>>(Wv, Wvt, H, H);
  transpose_cvt_f32_bf16<<<dim3(32, 32), 256, 0, stream>>>(Wo, Wot, H, H);
  // 3) collapsed embed matrices + bias fold
  k2_cqk<<<512, 256, 0, stream>>>(Wq, Wk, We, Cqk);
  k2b_dvec<<<1, 64, 0, stream>>>(bq, bk, We, be, dvec);
  // 4) unit-norm quantum embeds (fp32)
  k3_embed<<<MROWS / 4, 256, 0, stream>>>(x, Cqk, dvec, qq, kk);
  // 5) v = x@Wv + bv  (bf16 MFMA)
  gemm_bt<0, 1, 0><<<dim3(8, 64, 1), 256, 0, stream>>>(
      xbf, Wvt, v, bv, nullptr, MROWS, H, H, 0, 0, 0, 0);
  // 6) v^T per batch
  transpose_bf16_batched<<<dim3(32, 64, BATCH), 256, 0, stream>>>(
      v, v_t, SEQ, H, (long)SEQ * H, (long)H * SEQ);
  // 7) attention weights P = exp(ov^2), rowsum
  k4_weights<<<dim3(SEQ / 16, BATCH), 256, 0, stream>>>(qq, kk, P, rowsum);
  // 8) attended = (P @ v) / rowsum  (bf16 out)
  gemm_bt<0, 0, 1><<<dim3(8, 16, BATCH), 256, 0, stream>>>(
      P, v_t, attn, nullptr, rowsum, SEQ, H, SEQ, (long)SEQ * SEQ, (long)H * SEQ,
      (long)SEQ * H, SEQ);
  // 9) out = attended @ Wo + bo  (fp32 out)
  gemm_bt<1, 1, 0><<<dim3(8, 64, 1), 256, 0, stream>>>(
      attn, Wot, out, bo, nullptr, MROWS, H, H, 0, 0, 0, 0);
}

// Round 2
// 320.226 us; speedup vs baseline: 1.1200x; 1.1200x over previous
//
#include <hip/hip_runtime.h>

#define H 1024
#define QD 16
#define BATCH 4
#define SEQ 2048
#define MROWS 8192  // BATCH*SEQ

typedef __bf16 bf16x8 __attribute__((ext_vector_type(8)));
typedef __bf16 bf16x4 __attribute__((ext_vector_type(4)));
typedef float f32x4 __attribute__((ext_vector_type(4)));

__device__ __forceinline__ void async_g2l_16(const void* g, void* l) {
  __builtin_amdgcn_global_load_lds(
      (const __attribute__((address_space(1))) unsigned int*)g,
      (__attribute__((address_space(3))) unsigned int*)l, 16, 0, 0);
}

// ---------------- fp32 -> bf16 hi/lo split (x) ----------------
__global__ __launch_bounds__(256) void cvt_split(const float* __restrict__ src,
                                                 __bf16* __restrict__ hi,
                                                 __bf16* __restrict__ lo, int n) {
  int i = (blockIdx.x * 256 + threadIdx.x) * 4;
  if (i < n) {
    float4 f = *(const float4*)(src + i);
    bf16x4 h, l;
    h[0] = (__bf16)f.x; l[0] = (__bf16)(f.x - (float)h[0]);
    h[1] = (__bf16)f.y; l[1] = (__bf16)(f.y - (float)h[1]);
    h[2] = (__bf16)f.z; l[2] = (__bf16)(f.z - (float)h[2]);
    h[3] = (__bf16)f.w; l[3] = (__bf16)(f.w - (float)h[3]);
    *(bf16x4*)(hi + i) = h;
    *(bf16x4*)(lo + i) = l;
  }
}

// ---------------- fp32 [R][C] -> bf16 transposed [C][R] ----------------
__global__ __launch_bounds__(256) void transpose_cvt_f32_bf16(
    const float* __restrict__ src, __bf16* __restrict__ dst, int R, int C) {
  __shared__ float t[32][33];
  const int rb = blockIdx.y * 32, cb = blockIdx.x * 32;
  const int c = threadIdx.x & 31;
  const int r0 = threadIdx.x >> 5;
#pragma unroll
  for (int rr = r0; rr < 32; rr += 8)
    t[rr][c] = src[(long)(rb + rr) * C + cb + c];
  __syncthreads();
#pragma unroll
  for (int rr = r0; rr < 32; rr += 8)
    dst[(long)(cb + rr) * R + rb + c] = (__bf16)t[c][rr];
}

// ---------------- bf16 [R][C] -> bf16 transposed [C][R], batched ----------------
__global__ __launch_bounds__(256) void transpose_bf16_batched(
    const __bf16* __restrict__ src, __bf16* __restrict__ dst, int R, int C,
    long sS, long sD) {
  __shared__ __bf16 t[32][33];
  const __bf16* s = src + (long)blockIdx.z * sS;
  __bf16* d = dst + (long)blockIdx.z * sD;
  const int rb = blockIdx.y * 32, cb = blockIdx.x * 32;
  const int c = threadIdx.x & 31;
  const int r0 = threadIdx.x >> 5;
#pragma unroll
  for (int rr = r0; rr < 32; rr += 8)
    t[rr][c] = s[(long)(rb + rr) * C + cb + c];
  __syncthreads();
#pragma unroll
  for (int rr = r0; rr < 32; rr += 8)
    d[(long)(cb + rr) * R + rb + c] = t[c][rr];
}

// ---------------- CqkT (Bt layout [32][1024]) in bf16 hi/lo ----------------
__global__ __launch_bounds__(256) void k2_cqk(const float* __restrict__ Wq,
                                              const float* __restrict__ Wk,
                                              const float* __restrict__ We,
                                              __bf16* __restrict__ Cth,
                                              __bf16* __restrict__ Ctl) {
  const int gw = blockIdx.x * 4 + (threadIdx.x >> 6);  // 0..2047
  const int lane = threadIdx.x & 63;
  const int mat = gw & 1, k = gw >> 1;
  const float* Wrow = (mat ? Wk : Wq) + (long)k * H;
  const int col = lane & 15, q4 = lane >> 4;
  float acc = 0.f;
  for (int n0 = 0; n0 < 256; ++n0) {
    int n = q4 * 256 + n0;
    acc += Wrow[n] * We[n * QD + col];
  }
  acc += __shfl_xor(acc, 16);
  acc += __shfl_xor(acc, 32);
  if (lane < 16) {
    __bf16 hi = (__bf16)acc;
    __bf16 lo = (__bf16)(acc - (float)hi);
    long idx = (long)(mat * 16 + col) * H + k;
    Cth[idx] = hi;
    Ctl[idx] = lo;
  }
}

// ---------------- dvec[j] = (bq|bk)@We + be ----------------
__global__ void k2b_dvec(const float* __restrict__ bq, const float* __restrict__ bk,
                         const float* __restrict__ We, const float* __restrict__ be,
                         float* __restrict__ dvec) {
  int j = threadIdx.x;
  if (j < 32) {
    int mat = j >> 4, col = j & 15;
    const float* b = mat ? bk : bq;
    float acc = be[col];
    for (int n = 0; n < H; ++n) acc += b[n] * We[n * QD + col];
    dvec[j] = acc;
  }
}

// ---------------- embed via MFMA (hi/lo split), fused normalize ----------------
__global__ __launch_bounds__(256) void k3_embed_mfma(
    const __bf16* __restrict__ xh, const __bf16* __restrict__ xl,
    const __bf16* __restrict__ Cth, const __bf16* __restrict__ Ctl,
    const float* __restrict__ dvec, float* __restrict__ qq,
    float* __restrict__ kk) {
  __shared__ __bf16 Ah[32 * 64];
  __shared__ __bf16 Al[32 * 64];
  __shared__ __bf16 Bh[32 * 64];
  __shared__ __bf16 Bl[32 * 64];
  const int tid = threadIdx.x;
  const int lane = tid & 63;
  const int w = tid >> 6;
  const int rowhalf = w >> 1;  // 0/1 -> rows 0-15 / 16-31
  const int ntile = w & 1;     // 0 -> qq, 1 -> kk
  const long rowBase = (long)blockIdx.x * 32;

  const int srow = tid >> 3;       // 0..31
  const int skk = (tid & 7) * 8;   // 0,8,..,56
  const __bf16* agh = xh + (rowBase + srow) * H + skk;
  const __bf16* agl = xl + (rowBase + srow) * H + skk;
  const __bf16* bgh = Cth + (long)srow * H + skk;
  const __bf16* bgl = Ctl + (long)srow * H + skk;
  __bf16* lah = &Ah[srow * 64 + skk];
  __bf16* lal = &Al[srow * 64 + skk];
  __bf16* lbh = &Bh[srow * 64 + skk];
  __bf16* lbl = &Bl[srow * 64 + skk];

  f32x4 acc;
  acc[0] = 0.f; acc[1] = 0.f; acc[2] = 0.f; acc[3] = 0.f;
  const int afrag0 = (rowhalf * 16 + (lane & 15)) * 64 + ((lane >> 4) * 8);
  const int bfrag0 = (ntile * 16 + (lane & 15)) * 64 + ((lane >> 4) * 8);

  for (int k0 = 0; k0 < H; k0 += 64) {
    async_g2l_16(agh + k0, lah);
    async_g2l_16(agl + k0, lal);
    async_g2l_16(bgh + k0, lbh);
    async_g2l_16(bgl + k0, lbl);
    __syncthreads();
#pragma unroll
    for (int s = 0; s < 2; ++s) {
      bf16x8 fah = *(const bf16x8*)&Ah[afrag0 + s * 32];
      bf16x8 fal = *(const bf16x8*)&Al[afrag0 + s * 32];
      bf16x8 fbh = *(const bf16x8*)&Bh[bfrag0 + s * 32];
      bf16x8 fbl = *(const bf16x8*)&Bl[bfrag0 + s * 32];
      acc = __builtin_amdgcn_mfma_f32_16x16x32_bf16(fah, fbh, acc, 0, 0, 0);
      acc = __builtin_amdgcn_mfma_f32_16x16x32_bf16(fal, fbh, acc, 0, 0, 0);
      acc = __builtin_amdgcn_mfma_f32_16x16x32_bf16(fah, fbl, acc, 0, 0, 0);
    }
    __syncthreads();
  }

  const float dv = dvec[ntile * 16 + (lane & 15)];
  float* outp = ntile ? kk : qq;
  const int quad = lane >> 4;
#pragma unroll
  for (int r = 0; r < 4; ++r) {
    float z = acc[r] + dv;
    float s2 = z * z;
    s2 += __shfl_xor(s2, 1);
    s2 += __shfl_xor(s2, 2);
    s2 += __shfl_xor(s2, 4);
    s2 += __shfl_xor(s2, 8);
    float val = z * rsqrtf(s2 + 1e-8f);
    long row = rowBase + rowhalf * 16 + quad * 4 + r;
    outp[row * QD + (lane & 15)] = val;
  }
}

// ---------------- P = exp((qq.kk)^2) bf16, rowsum fp32 ----------------
__global__ __launch_bounds__(256) void k4_weights(const float* __restrict__ qq,
                                                  const float* __restrict__ kk,
                                                  __bf16* __restrict__ P,
                                                  float* __restrict__ rowsum) {
  const int b = blockIdx.y;
  const int qbase = blockIdx.x * 16;
  const int tid = threadIdx.x;
  __shared__ float qs[16][16];
  __shared__ float rsh[16];
  qs[tid >> 4][tid & 15] =
      qq[((long)b * SEQ + qbase + (tid >> 4)) * QD + (tid & 15)];
  if (tid < 16) rsh[tid] = 0.f;
  __syncthreads();
  float sums[16];
#pragma unroll
  for (int q = 0; q < 16; ++q) sums[q] = 0.f;
  const float* kkb = kk + (long)b * SEQ * QD;
  __bf16* Pb = P + ((long)b * SEQ + qbase) * SEQ;
  for (int kc = 0; kc < 8; ++kc) {
    const int k = kc * 256 + tid;
    const float4* kp = (const float4*)(kkb + (long)k * QD);
    float4 k0 = kp[0], k1 = kp[1], k2 = kp[2], k3 = kp[3];
    float kr[16] = {k0.x, k0.y, k0.z, k0.w, k1.x, k1.y, k1.z, k1.w,
                    k2.x, k2.y, k2.z, k2.w, k3.x, k3.y, k3.z, k3.w};
#pragma unroll
    for (int q = 0; q < 16; ++q) {
      float d = 0.f;
#pragma unroll
      for (int j = 0; j < 16; ++j) d += qs[q][j] * kr[j];
      float wgt = __expf(d * d);
      sums[q] += wgt;
      Pb[(long)q * SEQ + k] = (__bf16)wgt;
    }
  }
#pragma unroll
  for (int q = 0; q < 16; ++q) {
    float vs = sums[q];
    vs += __shfl_xor(vs, 1);
    vs += __shfl_xor(vs, 2);
    vs += __shfl_xor(vs, 4);
    vs += __shfl_xor(vs, 8);
    vs += __shfl_xor(vs, 16);
    vs += __shfl_xor(vs, 32);
    if ((tid & 63) == 0) atomicAdd(&rsh[q], vs);
  }
  __syncthreads();
  if (tid < 16) rowsum[(long)b * SEQ + qbase + tid] = rsh[tid];
}

// ---------------- m97-style GEMM: C = A[MxK] @ Bt[NxK]^T (+bias)(*1/rowsum) ----------------
template <int OUTF32, int HASBIAS, int HASSCALE>
__global__ __launch_bounds__(256) void gemm_bt(
    const __bf16* __restrict__ A, const __bf16* __restrict__ Bt,
    void* __restrict__ Cout, const float* __restrict__ bias,
    const float* __restrict__ rowscale, int M, int N, int K,
    long sA, long sB, long sC, long sS) {
  __shared__ __bf16 Alds[128 * 64];
  __shared__ __bf16 Blds[128 * 64];
  const int tid = threadIdx.x;
  const int lane = tid & 63;
  const int w = tid >> 6;
  const int wm = w >> 1, wn = w & 1;
  const int bz = blockIdx.z;
  const long rowBase = (long)blockIdx.y * 128;
  const long colBase = (long)blockIdx.x * 128;
  const __bf16* Ab = A + (long)bz * sA;
  const __bf16* Bb = Bt + (long)bz * sB;

  const int srow = lane >> 3;
  const int skk = (lane & 7) * 8;

  const __bf16* ag[4];
  const __bf16* bg[4];
  __bf16* as_[4];
  __bf16* bs_[4];
#pragma unroll
  for (int j = 0; j < 4; ++j) {
    int r = j * 32 + w * 8;
    ag[j] = Ab + (rowBase + r + srow) * (long)K + skk;
    bg[j] = Bb + (colBase + r + srow) * (long)K + skk;
    as_[j] = &Alds[r * 64];
    bs_[j] = &Blds[r * 64];
  }

  f32x4 acc[4][4];
#pragma unroll
  for (int i = 0; i < 4; ++i)
#pragma unroll
    for (int j = 0; j < 4; ++j) {
      acc[i][j][0] = 0.f; acc[i][j][1] = 0.f; acc[i][j][2] = 0.f; acc[i][j][3] = 0.f;
    }

  const int afrag0 = (wm * 64 + (lane & 15)) * 64 + ((lane >> 4) * 8);
  const int bfrag0 = (wn * 64 + (lane & 15)) * 64 + ((lane >> 4) * 8);

  for (int k0 = 0; k0 < K; k0 += 64) {
#pragma unroll
    for (int j = 0; j < 4; ++j) {
      async_g2l_16(ag[j], as_[j]);
      async_g2l_16(bg[j], bs_[j]);
      ag[j] += 64;
      bg[j] += 64;
    }
    __syncthreads();
#pragma unroll
    for (int s = 0; s < 2; ++s) {
      bf16x8 af[4], bfv[4];
#pragma unroll
      for (int i = 0; i < 4; ++i) {
        af[i] = *(const bf16x8*)&Alds[afrag0 + i * 16 * 64 + s * 32];
        bfv[i] = *(const bf16x8*)&Blds[bfrag0 + i * 16 * 64 + s * 32];
      }
#pragma unroll
      for (int i = 0; i < 4; ++i)
#pragma unroll
        for (int j = 0; j < 4; ++j)
          acc[i][j] =
              __builtin_amdgcn_mfma_f32_16x16x32_bf16(af[i], bfv[j], acc[i][j], 0, 0, 0);
    }
    __syncthreads();
  }

  const float* rs = HASSCALE ? (rowscale + (long)bz * sS) : (const float*)nullptr;
  const long crow0 = rowBase + wm * 64 + ((lane >> 4) * 4);
  const long ccol0 = colBase + wn * 64 + (lane & 15);
#pragma unroll
  for (int i = 0; i < 4; ++i) {
#pragma unroll
    for (int j = 0; j < 4; ++j) {
      long col = ccol0 + j * 16;
      float bb = HASBIAS ? bias[col] : 0.f;
#pragma unroll
      for (int r = 0; r < 4; ++r) {
        long row = crow0 + i * 16 + r;
        float val = acc[i][j][r] + bb;
        if (HASSCALE) val *= 1.0f / rs[row];
        if (OUTF32)
          ((float*)Cout)[(long)bz * sC + row * N + col] = val;
        else
          ((__bf16*)Cout)[(long)bz * sC + row * N + col] = (__bf16)val;
      }
    }
  }
}

extern "C" void kernel_launch(void* const* d_in, const int* in_sizes, int n_in,
                              void* d_out, int out_size, void* d_ws, size_t ws_size,
                              hipStream_t stream) {
  const float* x = (const float*)d_in[0];
  const float* Wq = (const float*)d_in[1];
  const float* bq = (const float*)d_in[2];
  const float* Wk = (const float*)d_in[3];
  const float* bk = (const float*)d_in[4];
  const float* Wv = (const float*)d_in[5];
  const float* bv = (const float*)d_in[6];
  const float* We = (const float*)d_in[7];
  const float* be = (const float*)d_in[8];
  const float* Wo = (const float*)d_in[9];
  const float* bo = (const float*)d_in[10];
  float* out = (float*)d_out;

  char* ws = (char*)d_ws;
  size_t o = 0;
  auto alloc = [&](size_t n) {
    size_t r = o;
    o += (n + 255) & ~(size_t)255;
    return r;
  };
  __bf16* xbf = (__bf16*)(ws + alloc((size_t)MROWS * H * 2));   // x hi
  __bf16* v = (__bf16*)(ws + alloc((size_t)MROWS * H * 2));
  __bf16* P = (__bf16*)(ws + alloc((size_t)BATCH * SEQ * SEQ * 2));
  __bf16* attn = (__bf16*)(ws + alloc((size_t)MROWS * H * 2));
  __bf16* Wvt = (__bf16*)(ws + alloc((size_t)H * H * 2));
  __bf16* Wot = (__bf16*)(ws + alloc((size_t)H * H * 2));
  __bf16* Cth = (__bf16*)(ws + alloc((size_t)32 * H * 2));
  __bf16* Ctl = (__bf16*)(ws + alloc((size_t)32 * H * 2));
  float* dvec = (float*)(ws + alloc(32 * 4));
  float* qq = (float*)(ws + alloc((size_t)MROWS * QD * 4));
  float* kk = (float*)(ws + alloc((size_t)MROWS * QD * 4));
  float* rowsum = (float*)(ws + alloc((size_t)MROWS * 4));
  // Aliases (stream-ordered lifetime separation):
  __bf16* xlo = attn;  // x lo part: dead before attn is written (step 8)
  __bf16* v_t = xbf;   // v^T: xbf dead after step 5 GEMM
  if (ws_size < o) return;

  // 1) x -> bf16 hi/lo split
  cvt_split<<<MROWS * H / 1024, 256, 0, stream>>>(x, xbf, xlo, MROWS * H);
  // 2) Wv^T, Wo^T as bf16
  transpose_cvt_f32_bf16<<<dim3(32, 32), 256, 0, stream>>>(Wv, Wvt, H, H);
  transpose_cvt_f32_bf16<<<dim3(32, 32), 256, 0, stream>>>(Wo, Wot, H, H);
  // 3) collapsed embed matrices (bf16 hi/lo, Bt layout) + bias fold
  k2_cqk<<<512, 256, 0, stream>>>(Wq, Wk, We, Cth, Ctl);
  k2b_dvec<<<1, 64, 0, stream>>>(bq, bk, We, be, dvec);
  // 4) unit-norm quantum embeds via MFMA (hi/lo split ~ fp32 precision)
  k3_embed_mfma<<<MROWS / 32, 256, 0, stream>>>(xbf, xlo, Cth, Ctl, dvec, qq, kk);
  // 5) v = x@Wv + bv  (bf16 MFMA)
  gemm_bt<0, 1, 0><<<dim3(8, 64, 1), 256, 0, stream>>>(
      xbf, Wvt, v, bv, nullptr, MROWS, H, H, 0, 0, 0, 0);
  // 6) v^T per batch
  transpose_bf16_batched<<<dim3(32, 64, BATCH), 256, 0, stream>>>(
      v, v_t, SEQ, H, (long)SEQ * H, (long)H * SEQ);
  // 7) attention weights P = exp(ov^2), rowsum
  k4_weights<<<dim3(SEQ / 16, BATCH), 256, 0, stream>>>(qq, kk, P, rowsum);
  // 8) attended = (P @ v) / rowsum  (bf16 out)
  gemm_bt<0, 0, 1><<<dim3(8, 16, BATCH), 256, 0, stream>>>(
      P, v_t, attn, nullptr, rowsum, SEQ, H, SEQ, (long)SEQ * SEQ, (long)H * SEQ,
      (long)SEQ * H, SEQ);
  // 9) out = attended @ Wo + bo  (fp32 out)
  gemm_bt<1, 1, 0><<<dim3(8, 64, 1), 256, 0, stream>>>(
      attn, Wot, out, bo, nullptr, MROWS, H, H, 0, 0, 0, 0);
}